// Round 6
// baseline (825.413 us; speedup 1.0000x reference)
//
#include <hip/hip_runtime.h>
#include <hip/hip_bf16.h>
#include <math.h>

#define NCH 32
#define BSH 6                   // nodes per bucket = 64
#define BNODES (1 << BSH)
#define MAXNB 2048              // LDS histogram capacity (N <= 131072)
#define PCH 1024                // payload LDS staging chunk (ints)

typedef unsigned short ushort_t;
typedef unsigned int uint_t;

static __device__ __forceinline__ float bf2f(ushort_t b) {
    return __uint_as_float(((uint_t)b) << 16);
}
static __device__ __forceinline__ ushort_t f2bf(float f) {
    __hip_bfloat16 h = __float2bfloat16(f);   // round-to-nearest-even
    return *reinterpret_cast<ushort_t*>(&h);
}

// ===========================================================================
// u = (W1-W2) x  (fp32, read LDS-locally per bucket)
// vh = W2 x      (bf16, the random-gather operand: 6.4 MB working set)
// y_e = u[src] + vh[tgt]
// k_gperm: gather vh ONCE per edge (bucket-ordered), fuse BN stats, emit
//          vperm (bucket-ordered bf16 copy) so apply is pure streaming.
// ===========================================================================

// --- per-node u (fp32) and vh (bf16) ---------------------------------------
__global__ __launch_bounds__(256) void k_uv(
    const float* __restrict__ x, const float* __restrict__ W,
    float* __restrict__ u, ushort_t* __restrict__ vh, int N)
{
    const int n = blockIdx.x * 256 + threadIdx.x;
    if (n >= N) return;
    float xs[NCH];
    const float4* __restrict__ ps = (const float4*)(x + (size_t)n * NCH);
#pragma unroll
    for (int i = 0; i < 8; ++i) {
        float4 a = ps[i];
        xs[4*i+0] = a.x; xs[4*i+1] = a.y; xs[4*i+2] = a.z; xs[4*i+3] = a.w;
    }
    float uu[NCH], vv[NCH];
#pragma unroll
    for (int c = 0; c < NCH; ++c) {
        const float* __restrict__ wr = W + c * 64;   // uniform -> s_load
        float su = 0.f, sv = 0.f;
#pragma unroll
        for (int k = 0; k < NCH; ++k) {
            su = fmaf(wr[k] - wr[32 + k], xs[k], su);
            sv = fmaf(wr[32 + k], xs[k], sv);
        }
        uu[c] = su; vv[c] = sv;
    }
    float4* __restrict__ pu = (float4*)(u + (size_t)n * NCH);
#pragma unroll
    for (int i = 0; i < 8; ++i)
        pu[i] = make_float4(uu[4*i], uu[4*i+1], uu[4*i+2], uu[4*i+3]);
    uint_t* __restrict__ pv = (uint_t*)(vh + (size_t)n * NCH);
#pragma unroll
    for (int i = 0; i < 16; ++i)
        pv[i] = (uint_t)f2bf(vv[2*i]) | ((uint_t)f2bf(vv[2*i+1]) << 16);
}

// --- bucket counts via LDS-privatized histogram ----------------------------
__global__ __launch_bounds__(256) void k_count(
    const int* __restrict__ srci, int* __restrict__ cnt_b, int E, int NB)
{
    __shared__ int h[MAXNB];
    for (int i = threadIdx.x; i < NB; i += 256) h[i] = 0;
    __syncthreads();
    const int stride = gridDim.x * 256;
    for (int e = blockIdx.x * 256 + threadIdx.x; e < E; e += stride)
        atomicAdd(&h[srci[e] >> BSH], 1);
    __syncthreads();
    for (int i = threadIdx.x; i < NB; i += 256)
        if (h[i]) atomicAdd(&cnt_b[i], h[i]);
}

// --- one-block exclusive scan over NB bucket counts ------------------------
__global__ __launch_bounds__(256) void k_scan_b(
    const int* __restrict__ cnt_b, int* __restrict__ off_b,
    int* __restrict__ cur_b, int NB)
{
    __shared__ int segsum[256];
    __shared__ int segoff[256];
    const int tid = threadIdx.x;
    const int per = (NB + 255) / 256;
    const int lo = tid * per;
    const int hi = min(lo + per, NB);
    int s = 0;
    for (int i = lo; i < hi; ++i) s += cnt_b[i];
    segsum[tid] = s;
    __syncthreads();
    if (tid == 0) {
        int a = 0;
        for (int i = 0; i < 256; ++i) { segoff[i] = a; a += segsum[i]; }
    }
    __syncthreads();
    int run = segoff[tid];
    for (int i = lo; i < hi; ++i) {
        off_b[i] = run;
        cur_b[i] = run;
        run += cnt_b[i];
    }
}

// --- scatter edges into buckets: payload = (src&63)<<17 | tgt --------------
__global__ __launch_bounds__(256) void k_bucket2(
    const int* __restrict__ srci, const int* __restrict__ tgti,
    int* __restrict__ cur_b, int* __restrict__ payload, int E)
{
    const int e = blockIdx.x * 256 + threadIdx.x;
    if (e >= E) return;
    const int s = srci[e];
    const int b = s >> BSH;
    const int pos = atomicAdd(&cur_b[b], 1);
    payload[pos] = ((s & (BNODES - 1)) << 17) | tgti[e];
}

// --- the ONE gather pass: vh[t] -> vperm (bucket-ordered) + BN stats -------
__global__ __launch_bounds__(256) void k_gperm(
    const float* __restrict__ u, const ushort_t* __restrict__ vh,
    const int* __restrict__ payload, const int* __restrict__ off_b,
    const int* __restrict__ cnt_b,
    ushort_t* __restrict__ vperm, float* __restrict__ partials, int N)
{
    __shared__ float uL[BNODES * NCH];
    __shared__ int pL[PCH];
    __shared__ float red[2][256];
    const int b = blockIdx.x;
    const int base = (b << BSH) * NCH;
    const int lim = N * NCH;
    for (int i = threadIdx.x; i < BNODES * NCH; i += 256) {
        const int gi = base + i;
        uL[i] = (gi < lim) ? u[gi] : 0.f;
    }

    const int off = off_b[b];
    const int cnt = cnt_b[b];
    const int g = threadIdx.x >> 5;     // edge sub-lane 0..7
    const int c = threadIdx.x & 31;     // channel
    float sum = 0.f, ssq = 0.f;

    for (int chunk = 0; chunk < cnt; chunk += PCH) {
        const int m = min(PCH, cnt - chunk);
        __syncthreads();
        for (int i = threadIdx.x; i < m; i += 256) pL[i] = payload[off + chunk + i];
        __syncthreads();
        int i = g;
        for (; i + 64 <= m; i += 64) {          // batch of 8 edges per group
            int w[8]; ushort_t vb[8];
#pragma unroll
            for (int k = 0; k < 8; ++k) w[k] = pL[i + 8*k];
#pragma unroll
            for (int k = 0; k < 8; ++k)
                vb[k] = vh[(size_t)(w[k] & 0x1FFFF) * NCH + c];   // 8 indep gathers
#pragma unroll
            for (int k = 0; k < 8; ++k) {
                const float y = uL[((w[k] >> 17) << 5) + c] + bf2f(vb[k]);
                sum += y;
                ssq = fmaf(y, y, ssq);
                vperm[(size_t)(off + chunk + i + 8*k) * NCH + c] = vb[k];
            }
        }
        for (; i < m; i += 8) {                 // tail
            const int w = pL[i];
            const ushort_t vb = vh[(size_t)(w & 0x1FFFF) * NCH + c];
            const float y = uL[((w >> 17) << 5) + c] + bf2f(vb);
            sum += y;
            ssq = fmaf(y, y, ssq);
            vperm[(size_t)(off + chunk + i) * NCH + c] = vb;
        }
    }

    red[0][threadIdx.x] = sum;
    red[1][threadIdx.x] = ssq;
    __syncthreads();
    if (threadIdx.x < 64) {
        const int which = threadIdx.x >> 5;   // 0: sum, 1: ssq
        const int cc = threadIdx.x & 31;
        float a = 0.f;
#pragma unroll
        for (int gg = 0; gg < 8; ++gg) a += red[which][(gg << 5) + cc];
        partials[(size_t)b * 64 + (which << 5) + cc] = a;
    }
}

// --- combine partials -> BN affine a,b -------------------------------------
__global__ __launch_bounds__(256) void k_finalize(
    const float* __restrict__ partials, int nblocks,
    const float* __restrict__ gamma, const float* __restrict__ beta,
    float* __restrict__ ab, float invE)
{
    __shared__ float acc[4][64];
    const int vtx = threadIdx.x & 63, chunk = threadIdx.x >> 6;
    float s = 0.f;
    for (int r = chunk; r < nblocks; r += 4) s += partials[(size_t)r * 64 + vtx];
    acc[chunk][vtx] = s;
    __syncthreads();
    if (threadIdx.x < 64) acc[0][vtx] = acc[0][vtx] + acc[1][vtx] + acc[2][vtx] + acc[3][vtx];
    __syncthreads();
    if (threadIdx.x < 32) {
        const int c = threadIdx.x;
        float mean = acc[0][c] * invE;
        float var  = acc[0][32 + c] * invE - mean * mean;
        float rstd = rsqrtf(var + 1e-5f);
        float a = gamma[c] * rstd;
        ab[c] = a; ab[32 + c] = beta[c] - mean * a;
    }
}

// --- apply: STREAMING vperm read, LDS accumulate, coalesced store ----------
__global__ __launch_bounds__(256) void k_apply_v2(
    const float* __restrict__ u, const ushort_t* __restrict__ vperm,
    const int* __restrict__ payload, const int* __restrict__ off_b,
    const int* __restrict__ cnt_b, const float* __restrict__ ab,
    float* __restrict__ out, int N)
{
    __shared__ float uL[BNODES * NCH];
    __shared__ float accL[BNODES * NCH];
    __shared__ int pL[PCH];
    const int b = blockIdx.x;
    const int base = (b << BSH) * NCH;
    const int lim = N * NCH;
    for (int i = threadIdx.x; i < BNODES * NCH; i += 256) {
        const int gi = base + i;
        uL[i] = (gi < lim) ? u[gi] : 0.f;
        accL[i] = 0.f;
    }

    const int off = off_b[b];
    const int cnt = cnt_b[b];
    const int g = threadIdx.x >> 5;
    const int c = threadIdx.x & 31;
    const float a_c = ab[c];
    const float b_c = ab[32 + c];

    for (int chunk = 0; chunk < cnt; chunk += PCH) {
        const int m = min(PCH, cnt - chunk);
        __syncthreads();
        for (int i = threadIdx.x; i < m; i += 256) pL[i] = payload[off + chunk + i];
        __syncthreads();
        int i = g;
        for (; i + 64 <= m; i += 64) {
            int w[8]; ushort_t vb[8];
#pragma unroll
            for (int k = 0; k < 8; ++k) w[k] = pL[i + 8*k];
#pragma unroll
            for (int k = 0; k < 8; ++k)
                vb[k] = vperm[(size_t)(off + chunk + i + 8*k) * NCH + c];  // streaming
#pragma unroll
            for (int k = 0; k < 8; ++k) {
                const int sl = w[k] >> 17;
                const float y = uL[(sl << 5) + c] + bf2f(vb[k]);
                float z = fmaf(a_c, y, b_c);
                z = (z > 0.f) ? z : (__expf(z) - 1.0f);
                atomicAdd(&accL[(sl << 5) + c], z);   // ds_add_f32
            }
        }
        for (; i < m; i += 8) {
            const int w = pL[i];
            const int sl = w >> 17;
            const float y = uL[(sl << 5) + c]
                          + bf2f(vperm[(size_t)(off + chunk + i) * NCH + c]);
            float z = fmaf(a_c, y, b_c);
            z = (z > 0.f) ? z : (__expf(z) - 1.0f);
            atomicAdd(&accL[(sl << 5) + c], z);
        }
    }
    __syncthreads();
    for (int i = threadIdx.x; i < BNODES * NCH; i += 256) {
        const int gi = base + i;
        if (gi < lim) out[gi] = accL[i];
    }
}

// ===========================================================================
// FALLBACK (round-5 structure, bf16 gathers) — if ws can't hold vperm
// ===========================================================================
__global__ __launch_bounds__(256) void k_stats_fb(
    const float* __restrict__ u, const ushort_t* __restrict__ vh,
    const int* __restrict__ payload, const int* __restrict__ off_b,
    const int* __restrict__ cnt_b,
    float* __restrict__ partials, int N)
{
    __shared__ float uL[BNODES * NCH];
    __shared__ int pL[PCH];
    __shared__ float red[2][256];
    const int b = blockIdx.x;
    const int base = (b << BSH) * NCH;
    const int lim = N * NCH;
    for (int i = threadIdx.x; i < BNODES * NCH; i += 256) {
        const int gi = base + i;
        uL[i] = (gi < lim) ? u[gi] : 0.f;
    }
    const int off = off_b[b];
    const int cnt = cnt_b[b];
    const int g = threadIdx.x >> 5;
    const int c = threadIdx.x & 31;
    float sum = 0.f, ssq = 0.f;
    for (int chunk = 0; chunk < cnt; chunk += PCH) {
        const int m = min(PCH, cnt - chunk);
        __syncthreads();
        for (int i = threadIdx.x; i < m; i += 256) pL[i] = payload[off + chunk + i];
        __syncthreads();
        for (int i = g; i < m; i += 8) {
            const int w = pL[i];
            const float y = uL[((w >> 17) << 5) + c]
                          + bf2f(vh[(size_t)(w & 0x1FFFF) * NCH + c]);
            sum += y;
            ssq = fmaf(y, y, ssq);
        }
    }
    red[0][threadIdx.x] = sum;
    red[1][threadIdx.x] = ssq;
    __syncthreads();
    if (threadIdx.x < 64) {
        const int which = threadIdx.x >> 5;
        const int cc = threadIdx.x & 31;
        float a = 0.f;
#pragma unroll
        for (int gg = 0; gg < 8; ++gg) a += red[which][(gg << 5) + cc];
        partials[(size_t)b * 64 + (which << 5) + cc] = a;
    }
}

__global__ __launch_bounds__(256) void k_apply_fb(
    const float* __restrict__ u, const ushort_t* __restrict__ vh,
    const int* __restrict__ payload, const int* __restrict__ off_b,
    const int* __restrict__ cnt_b, const float* __restrict__ ab,
    float* __restrict__ out, int N)
{
    __shared__ float uL[BNODES * NCH];
    __shared__ float accL[BNODES * NCH];
    __shared__ int pL[PCH];
    const int b = blockIdx.x;
    const int base = (b << BSH) * NCH;
    const int lim = N * NCH;
    for (int i = threadIdx.x; i < BNODES * NCH; i += 256) {
        const int gi = base + i;
        uL[i] = (gi < lim) ? u[gi] : 0.f;
        accL[i] = 0.f;
    }
    const int off = off_b[b];
    const int cnt = cnt_b[b];
    const int g = threadIdx.x >> 5;
    const int c = threadIdx.x & 31;
    const float a_c = ab[c];
    const float b_c = ab[32 + c];
    for (int chunk = 0; chunk < cnt; chunk += PCH) {
        const int m = min(PCH, cnt - chunk);
        __syncthreads();
        for (int i = threadIdx.x; i < m; i += 256) pL[i] = payload[off + chunk + i];
        __syncthreads();
        for (int i = g; i < m; i += 8) {
            const int w = pL[i];
            const int sl = w >> 17;
            const float y = uL[(sl << 5) + c]
                          + bf2f(vh[(size_t)(w & 0x1FFFF) * NCH + c]);
            float z = fmaf(a_c, y, b_c);
            z = (z > 0.f) ? z : (__expf(z) - 1.0f);
            atomicAdd(&accL[(sl << 5) + c], z);
        }
    }
    __syncthreads();
    for (int i = threadIdx.x; i < BNODES * NCH; i += 256) {
        const int gi = base + i;
        if (gi < lim) out[gi] = accL[i];
    }
}

// ===========================================================================
extern "C" void kernel_launch(void* const* d_in, const int* in_sizes, int n_in,
                              void* d_out, int out_size, void* d_ws, size_t ws_size,
                              hipStream_t stream)
{
    const float* x     = (const float*)d_in[0];
    const int*   ei    = (const int*)d_in[1];
    const float* W     = (const float*)d_in[2];
    const float* gamma = (const float*)d_in[3];
    const float* beta  = (const float*)d_in[4];
    const int E = in_sizes[1] / 2;
    const int N = in_sizes[0] / NCH;
    const int* srci = ei;
    const int* tgti = ei + E;

    const int NB = (N + BNODES - 1) >> BSH;

    // common ws prefix: u[N*32]f32 | vh[N*32]bf16 | payload[E] | cnt/off/cur[NB*3]
    //                   | partials[NB*64]f32 | ab[64]f32 | (fast only) vperm[E*32]bf16
    size_t base_need = (size_t)N * NCH * 4 + (size_t)N * NCH * 2
                     + ((size_t)E + 3 * NB) * 4
                     + ((size_t)NB * 64 + 64) * 4;
    size_t vperm_bytes = (size_t)E * NCH * 2;

    float*    u       = (float*)d_ws;
    ushort_t* vh      = (ushort_t*)(u + (size_t)N * NCH);
    int*      payload = (int*)(vh + (size_t)N * NCH);
    int*      cnt_b   = payload + E;
    int*      off_b   = cnt_b + NB;
    int*      cur_b   = off_b + NB;
    float*    partials= (float*)(cur_b + NB);
    float*    ab      = partials + (size_t)NB * 64;
    ushort_t* vperm   = (ushort_t*)(ab + 64);

    hipMemsetAsync(cnt_b, 0, (size_t)NB * sizeof(int), stream);
    k_uv<<<(N + 255) / 256, 256, 0, stream>>>(x, W, u, vh, N);
    k_count<<<128, 256, 0, stream>>>(srci, cnt_b, E, NB);
    k_scan_b<<<1, 256, 0, stream>>>(cnt_b, off_b, cur_b, NB);
    k_bucket2<<<(E + 255) / 256, 256, 0, stream>>>(srci, tgti, cur_b, payload, E);

    if (N <= 131072 && NB <= MAXNB && ws_size >= base_need + vperm_bytes) {
        // FAST: single gather pass (fused stats) + streaming apply
        k_gperm<<<NB, 256, 0, stream>>>(u, vh, payload, off_b, cnt_b, vperm, partials, N);
        k_finalize<<<1, 256, 0, stream>>>(partials, NB, gamma, beta, ab, 1.0f / (float)E);
        k_apply_v2<<<NB, 256, 0, stream>>>(u, vperm, payload, off_b, cnt_b, ab,
                                           (float*)d_out, N);
    } else {
        // FALLBACK: two bf16-gather passes (round-5 structure)
        k_stats_fb<<<NB, 256, 0, stream>>>(u, vh, payload, off_b, cnt_b, partials, N);
        k_finalize<<<1, 256, 0, stream>>>(partials, NB, gamma, beta, ab, 1.0f / (float)E);
        k_apply_fb<<<NB, 256, 0, stream>>>(u, vh, payload, off_b, cnt_b, ab,
                                           (float*)d_out, N);
    }
}